// Round 5
// baseline (186.373 us; speedup 1.0000x reference)
//
#include <hip/hip_runtime.h>
#include <hip/hip_bf16.h>
#include <math.h>

#define DIM 1024
#define HEADS 16
#define HEAD_DIM 64
#define MAXSEQ 4096
#define BATCH 16
#define NBLK 64              // blocks per batch; block i owns rows i + NBLK*j
#define ROWS_PER_BLK (MAXSEQ / NBLK)  // 64
#define TILE 8

// ---------------- Kernel A: QKV projection ----------------
__global__ __launch_bounds__(256) void qkv_proj(
    const float* __restrict__ token,
    const float* __restrict__ Wq, const float* __restrict__ Wk,
    const float* __restrict__ Wv,
    float* __restrict__ out /* 3 x 16 x 1024 */) {
  __shared__ float tok[BATCH * DIM];  // 64 KiB
  for (int idx = threadIdx.x; idx < BATCH * DIM; idx += 256)
    tok[idx] = token[idx];
  __syncthreads();

  const float* W = (blockIdx.y == 0) ? Wq : ((blockIdx.y == 1) ? Wk : Wv);
  float* o = out + (size_t)blockIdx.y * BATCH * DIM;

  const int wave = threadIdx.x >> 6;
  const int lane = threadIdx.x & 63;
  const int i0 = blockIdx.x * 16 + wave * 4;

  float acc[4][16];
#pragma unroll
  for (int ii = 0; ii < 4; ++ii)
#pragma unroll
    for (int b = 0; b < 16; ++b) acc[ii][b] = 0.f;

  for (int t = 0; t < 16; ++t) {
    const int j = t * 64 + lane;
    float tk[16];
#pragma unroll
    for (int b = 0; b < 16; ++b) tk[b] = tok[b * DIM + j];
#pragma unroll
    for (int ii = 0; ii < 4; ++ii) {
      const float w = W[(size_t)(i0 + ii) * DIM + j];
#pragma unroll
      for (int b = 0; b < 16; ++b) acc[ii][b] = fmaf(w, tk[b], acc[ii][b]);
    }
  }

#pragma unroll
  for (int ii = 0; ii < 4; ++ii)
#pragma unroll
    for (int b = 0; b < 16; ++b) {
      float v = acc[ii][b];
#pragma unroll
      for (int m = 32; m >= 1; m >>= 1) v += __shfl_xor(v, m);
      if (lane == 0) o[(size_t)b * DIM + i0 + ii] = v;
    }
}

// ---------------- Kernel B: flash-decode partials, strided rows ----------------
// grid (NBLK, BATCH), block 256. Block i of batch b owns rows s = i + NBLK*j,
// j = 0..ROWS_PER_BLK-1. All 64 blocks of a batch advance j together, so the
// aggregate DRAM access per (batch, K/V) is ONE sliding contiguous 256 KB
// window -> 32 sequential super-streams chip-wide instead of ~2000 interleaved
// streams (DRAM bank-friendly). Online softmax is order-agnostic.
// Thread t: head t>>4, dims (t&15)*4..+4. No LDS, no __syncthreads.
// partial layout per (b,h,c): [m, l, acc[64]]  (66 floats), c = i.
__global__ __launch_bounds__(256) void attn_partial(
    const float* __restrict__ kc, const float* __restrict__ vc,
    const float* __restrict__ qkv, const int* __restrict__ pos_p,
    float* __restrict__ part) {
  const int i = blockIdx.x, b = blockIdx.y;
  const int t = threadIdx.x;
  const int h = t >> 4, lq = t & 15;
  const int pos = pos_p[0];
  const int nk = pos + 1;

  const float* qp   = qkv + (size_t)b * DIM;
  const float* knew = qkv + (size_t)BATCH * DIM + (size_t)b * DIM;
  const float* vnew = qkv + 2 * (size_t)BATCH * DIM + (size_t)b * DIM;
  const float* kbase = kc + (size_t)b * MAXSEQ * DIM;
  const float* vbase = vc + (size_t)b * MAXSEQ * DIM;

  const float scale = 0.125f;  // 1/sqrt(64)
  float4 q4 = *(const float4*)(qp + 4 * t);
  q4.x *= scale; q4.y *= scale; q4.z *= scale; q4.w *= scale;

  float m = -INFINITY, l = 0.f;
  float4 a4 = make_float4(0.f, 0.f, 0.f, 0.f);

  for (int j0 = 0; j0 < ROWS_PER_BLK; j0 += TILE) {
    // ---- issue K and V loads for the tile (independent, in flight) ----
    float4 k4[TILE], v4[TILE];
#pragma unroll
    for (int jj = 0; jj < TILE; ++jj) {
      const int s = i + NBLK * (j0 + jj);  // always < MAXSEQ
      const float* krow = (s == pos) ? knew : (kbase + (size_t)s * DIM);
      const float* vrow = (s == pos) ? vnew : (vbase + (size_t)s * DIM);
      k4[jj] = *(const float4*)(krow + 4 * t);
      v4[jj] = *(const float4*)(vrow + 4 * t);
    }

    // ---- partial dots ----
    float sc[TILE];
#pragma unroll
    for (int jj = 0; jj < TILE; ++jj)
      sc[jj] = q4.x * k4[jj].x + q4.y * k4[jj].y + q4.z * k4[jj].z +
               q4.w * k4[jj].w;

    // ---- independent 4-deep shfl reduce chains (ILP) ----
#pragma unroll
    for (int jj = 0; jj < TILE; ++jj) {
      sc[jj] += __shfl_xor(sc[jj], 1);
      sc[jj] += __shfl_xor(sc[jj], 2);
      sc[jj] += __shfl_xor(sc[jj], 4);
      sc[jj] += __shfl_xor(sc[jj], 8);
    }
#pragma unroll
    for (int jj = 0; jj < TILE; ++jj)
      if (i + NBLK * (j0 + jj) >= nk) sc[jj] = -INFINITY;

    // ---- online softmax update (one rescale per tile) ----
    float tm = sc[0];
#pragma unroll
    for (int jj = 1; jj < TILE; ++jj) tm = fmaxf(tm, sc[jj]);
    const float m_new = fmaxf(m, tm);
    const float corr = (m_new == -INFINITY) ? 1.f : __expf(m - m_new);
    l *= corr;
    a4.x *= corr; a4.y *= corr; a4.z *= corr; a4.w *= corr;
    m = m_new;

#pragma unroll
    for (int jj = 0; jj < TILE; ++jj) {
      const float p = (sc[jj] == -INFINITY) ? 0.f : __expf(sc[jj] - m);
      l += p;
      a4.x = fmaf(p, v4[jj].x, a4.x);
      a4.y = fmaf(p, v4[jj].y, a4.y);
      a4.z = fmaf(p, v4[jj].z, a4.z);
      a4.w = fmaf(p, v4[jj].w, a4.w);
    }
  }

  const size_t base = (((size_t)(b * HEADS + h)) * NBLK + i) * 66;
  part[base + 2 + lq * 4 + 0] = a4.x;
  part[base + 2 + lq * 4 + 1] = a4.y;
  part[base + 2 + lq * 4 + 2] = a4.z;
  part[base + 2 + lq * 4 + 3] = a4.w;
  if (lq == 0) { part[base] = m; part[base + 1] = l; }
}

// ---------------- Kernel C: combine partials ----------------
__global__ __launch_bounds__(64) void attn_combine(
    const float* __restrict__ part, float* __restrict__ attn) {
  const int bh = blockIdx.x;
  const int b = bh >> 4, h = bh & 15;
  const int d = threadIdx.x;
  const float* p0 = part + (size_t)bh * NBLK * 66;
  float M = -INFINITY;
#pragma unroll
  for (int c = 0; c < NBLK; ++c) M = fmaxf(M, p0[c * 66]);
  float L = 0.f, o = 0.f;
#pragma unroll 8
  for (int c = 0; c < NBLK; ++c) {
    const float mc = p0[c * 66];
    if (mc > -INFINITY) {
      const float w = __expf(mc - M);
      L += p0[c * 66 + 1] * w;
      o = fmaf(p0[c * 66 + 2 + d], w, o);
    }
  }
  attn[(size_t)b * DIM + h * HEAD_DIM + d] = o / L;
}

// ---------------- Kernel D: output projection ----------------
__global__ __launch_bounds__(256) void o_proj(
    const float* __restrict__ attn, const float* __restrict__ Wo,
    float* __restrict__ out) {
  __shared__ float tok[BATCH * DIM];
  for (int idx = threadIdx.x; idx < BATCH * DIM; idx += 256)
    tok[idx] = attn[idx];
  __syncthreads();

  const int wave = threadIdx.x >> 6;
  const int lane = threadIdx.x & 63;
  const int i0 = blockIdx.x * 16 + wave * 4;

  float acc[4][16];
#pragma unroll
  for (int ii = 0; ii < 4; ++ii)
#pragma unroll
    for (int b = 0; b < 16; ++b) acc[ii][b] = 0.f;

  for (int t = 0; t < 16; ++t) {
    const int j = t * 64 + lane;
    float tk[16];
#pragma unroll
    for (int b = 0; b < 16; ++b) tk[b] = tok[b * DIM + j];
#pragma unroll
    for (int ii = 0; ii < 4; ++ii) {
      const float w = Wo[(size_t)(i0 + ii) * DIM + j];
#pragma unroll
      for (int b = 0; b < 16; ++b) acc[ii][b] = fmaf(w, tk[b], acc[ii][b]);
    }
  }

#pragma unroll
  for (int ii = 0; ii < 4; ++ii)
#pragma unroll
    for (int b = 0; b < 16; ++b) {
      float v = acc[ii][b];
#pragma unroll
      for (int m = 32; m >= 1; m >>= 1) v += __shfl_xor(v, m);
      if (lane == 0) out[(size_t)b * DIM + i0 + ii] = v;
    }
}

extern "C" void kernel_launch(void* const* d_in, const int* in_sizes, int n_in,
                              void* d_out, int out_size, void* d_ws, size_t ws_size,
                              hipStream_t stream) {
  const float* token = (const float*)d_in[0];
  const float* kc = (const float*)d_in[1];
  const float* vc = (const float*)d_in[2];
  const float* Wq = (const float*)d_in[3];
  const float* Wk = (const float*)d_in[4];
  const float* Wv = (const float*)d_in[5];
  const float* Wo = (const float*)d_in[6];
  const int* pos = (const int*)d_in[7];
  float* out = (float*)d_out;
  float* ws = (float*)d_ws;

  // workspace layout (floats):
  //  [0, 49152)   : q,k,v projections (3 x 16 x 1024)
  //  then         : attention partials 16*16*NBLK*66
  //  then         : combined attention output 16 x 1024
  float* qkv = ws;
  float* part = ws + 3 * BATCH * DIM;
  float* attn = part + (size_t)BATCH * HEADS * NBLK * 66;

  hipLaunchKernelGGL(qkv_proj, dim3(64, 3), dim3(256), 0, stream,
                     token, Wq, Wk, Wv, qkv);
  hipLaunchKernelGGL(attn_partial, dim3(NBLK, BATCH), dim3(256), 0,
                     stream, kc, vc, qkv, pos, part);
  hipLaunchKernelGGL(attn_combine, dim3(BATCH * HEADS), dim3(64), 0, stream,
                     part, attn);
  hipLaunchKernelGGL(o_proj, dim3(64), dim3(256), 0, stream, attn, Wo, out);
  (void)in_sizes; (void)n_in; (void)out_size; (void)ws_size;
}

// Round 6
// 177.719 us; speedup vs baseline: 1.0487x; 1.0487x over previous
//
#include <hip/hip_runtime.h>
#include <hip/hip_bf16.h>
#include <math.h>

#define DIM 1024
#define HEADS 16
#define HEAD_DIM 64
#define MAXSEQ 4096
#define BATCH 16
#define CHUNK 64                 // rows per block
#define NCHUNK (MAXSEQ / CHUNK)  // 64
#define TROWS 4                  // rows per pipeline tile
#define NTILE (CHUNK / TROWS)    // 16

// async global->LDS, 16B per lane, LDS dest = wave-uniform base + lane*16
__device__ __forceinline__ void gload_lds16(const float* g, float* l) {
  __builtin_amdgcn_global_load_lds(
      (const __attribute__((address_space(1))) void*)g,
      (__attribute__((address_space(3))) void*)l, 16, 0, 0);
}

// ---------------- Kernel A: QKV projection ----------------
__global__ __launch_bounds__(256) void qkv_proj(
    const float* __restrict__ token,
    const float* __restrict__ Wq, const float* __restrict__ Wk,
    const float* __restrict__ Wv,
    float* __restrict__ out /* 3 x 16 x 1024 */) {
  __shared__ float tok[BATCH * DIM];  // 64 KiB
  for (int idx = threadIdx.x; idx < BATCH * DIM; idx += 256)
    tok[idx] = token[idx];
  __syncthreads();

  const float* W = (blockIdx.y == 0) ? Wq : ((blockIdx.y == 1) ? Wk : Wv);
  float* o = out + (size_t)blockIdx.y * BATCH * DIM;

  const int wave = threadIdx.x >> 6;
  const int lane = threadIdx.x & 63;
  const int i0 = blockIdx.x * 16 + wave * 4;

  float acc[4][16];
#pragma unroll
  for (int ii = 0; ii < 4; ++ii)
#pragma unroll
    for (int b = 0; b < 16; ++b) acc[ii][b] = 0.f;

  for (int t = 0; t < 16; ++t) {
    const int j = t * 64 + lane;
    float tk[16];
#pragma unroll
    for (int b = 0; b < 16; ++b) tk[b] = tok[b * DIM + j];
#pragma unroll
    for (int ii = 0; ii < 4; ++ii) {
      const float w = W[(size_t)(i0 + ii) * DIM + j];
#pragma unroll
      for (int b = 0; b < 16; ++b) acc[ii][b] = fmaf(w, tk[b], acc[ii][b]);
    }
  }

#pragma unroll
  for (int ii = 0; ii < 4; ++ii)
#pragma unroll
    for (int b = 0; b < 16; ++b) {
      float v = acc[ii][b];
#pragma unroll
      for (int m = 32; m >= 1; m >>= 1) v += __shfl_xor(v, m);
      if (lane == 0) o[(size_t)b * DIM + i0 + ii] = v;
    }
}

// ---------------- Kernel B: flash-decode partials, LDS-DMA pipelined --------
// grid (NCHUNK, BATCH), block 256 = 4 waves. Block owns rows [64c, 64c+64).
// Wave w owns heads 4w..4w+3 = bytes [w*1KB, w*1KB+1KB) of every 4KB row ->
// waves are fully independent: NO __syncthreads, so no vmcnt(0) drain.
// Double-buffered tiles of TROWS rows staged via global_load_lds (8 x 1KB DMA
// per tile); steady state keeps 16 loads in flight per wave, enforced by
// hand-counted s_waitcnt vmcnt(8) + sched_barrier fences.
// Thread t: head t>>4, dims (t&15)*4..+4 (same as LDS linear layout).
// partial layout per (b,h,c): [m, l, acc[64]]  (66 floats)
__global__ __launch_bounds__(256, 2) void attn_partial(
    const float* __restrict__ kc, const float* __restrict__ vc,
    const float* __restrict__ qkv, const int* __restrict__ pos_p,
    float* __restrict__ part) {
  const int c = blockIdx.x, b = blockIdx.y;
  const int t = threadIdx.x;
  const int w = t >> 6, lane = t & 63;
  const int h = t >> 4, lq = t & 15;
  const int pos = pos_p[0];
  const int nk = pos + 1;
  const int s0 = c * CHUNK;

  // [wave][buf][K/V][row][256 floats] = 64 KiB
  __shared__ __align__(16) float smem[4][2][2][TROWS][256];

  const float* qp   = qkv + (size_t)b * DIM;
  const float* knew = qkv + (size_t)BATCH * DIM + (size_t)b * DIM;
  const float* vnew = qkv + 2 * (size_t)BATCH * DIM + (size_t)b * DIM;
  const float* kbase = kc + (size_t)b * MAXSEQ * DIM;
  const float* vbase = vc + (size_t)b * MAXSEQ * DIM;

  const float scale = 0.125f;  // 1/sqrt(64)
  float4 q4 = *(const float4*)(qp + 4 * t);
  q4.x *= scale; q4.y *= scale; q4.z *= scale; q4.w *= scale;
  // q4 now materialized (compiler waits here) before any DMA is issued
  __builtin_amdgcn_sched_barrier(0);

  // stage tile j (TROWS rows) into buffer p: 8 global_load_lds, 1KB each
  auto stage = [&](int j, int p) {
#pragma unroll
    for (int r = 0; r < TROWS; ++r) {
      const int s = s0 + j * TROWS + r;
      const float* kg = (s == pos) ? knew : (kbase + (size_t)s * DIM);
      const float* vg = (s == pos) ? vnew : (vbase + (size_t)s * DIM);
      gload_lds16(kg + (w << 8) + (lane << 2), &smem[w][p][0][r][0]);
      gload_lds16(vg + (w << 8) + (lane << 2), &smem[w][p][1][r][0]);
    }
  };

  stage(0, 0);
  stage(1, 1);

  float m = -INFINITY, lsum = 0.f;
  float4 a4 = make_float4(0.f, 0.f, 0.f, 0.f);

  for (int j = 0; j < NTILE; ++j) {
    const int p = j & 1;
    // tile j landed when <=8 loads (tile j+1's) remain outstanding
    asm volatile("s_waitcnt vmcnt(8)" ::: "memory");
    __builtin_amdgcn_sched_barrier(0);

    float4 k4[TROWS], v4[TROWS];
#pragma unroll
    for (int r = 0; r < TROWS; ++r) {
      k4[r] = *(const float4*)&smem[w][p][0][r][lane << 2];
      v4[r] = *(const float4*)&smem[w][p][1][r][lane << 2];
    }
    // all ds_reads retired before this buffer is overwritten
    asm volatile("s_waitcnt lgkmcnt(0)" ::: "memory");
    __builtin_amdgcn_sched_barrier(0);

    // prefetch tile j+2 into the buffer just consumed (clamped re-stage at
    // the tail keeps the vmcnt arithmetic exact; data is never read again)
    const int jn = (j + 2 < NTILE) ? (j + 2) : (NTILE - 1);
    stage(jn, p);
    __builtin_amdgcn_sched_barrier(0);

    // ---- compute tile j ----
    float sc[TROWS];
#pragma unroll
    for (int r = 0; r < TROWS; ++r)
      sc[r] = q4.x * k4[r].x + q4.y * k4[r].y + q4.z * k4[r].z +
              q4.w * k4[r].w;
#pragma unroll
    for (int r = 0; r < TROWS; ++r) {
      sc[r] += __shfl_xor(sc[r], 1);
      sc[r] += __shfl_xor(sc[r], 2);
      sc[r] += __shfl_xor(sc[r], 4);
      sc[r] += __shfl_xor(sc[r], 8);
    }
    const int srow = s0 + j * TROWS;
#pragma unroll
    for (int r = 0; r < TROWS; ++r)
      if (srow + r >= nk) sc[r] = -INFINITY;

    float tm = fmaxf(fmaxf(sc[0], sc[1]), fmaxf(sc[2], sc[3]));
    const float m_new = fmaxf(m, tm);
    const float corr = (m_new == -INFINITY) ? 1.f : __expf(m - m_new);
    lsum *= corr;
    a4.x *= corr; a4.y *= corr; a4.z *= corr; a4.w *= corr;
    m = m_new;

#pragma unroll
    for (int r = 0; r < TROWS; ++r) {
      const float pp = (sc[r] == -INFINITY) ? 0.f : __expf(sc[r] - m);
      lsum += pp;
      a4.x = fmaf(pp, v4[r].x, a4.x);
      a4.y = fmaf(pp, v4[r].y, a4.y);
      a4.z = fmaf(pp, v4[r].z, a4.z);
      a4.w = fmaf(pp, v4[r].w, a4.w);
    }
  }

  const size_t base = (((size_t)(b * HEADS + h)) * NCHUNK + c) * 66;
  part[base + 2 + lq * 4 + 0] = a4.x;
  part[base + 2 + lq * 4 + 1] = a4.y;
  part[base + 2 + lq * 4 + 2] = a4.z;
  part[base + 2 + lq * 4 + 3] = a4.w;
  if (lq == 0) { part[base] = m; part[base + 1] = lsum; }
}

// ---------------- Kernel C: combine partials ----------------
__global__ __launch_bounds__(64) void attn_combine(
    const float* __restrict__ part, float* __restrict__ attn) {
  const int bh = blockIdx.x;
  const int b = bh >> 4, h = bh & 15;
  const int d = threadIdx.x;
  const float* p0 = part + (size_t)bh * NCHUNK * 66;
  float M = -INFINITY;
#pragma unroll
  for (int c = 0; c < NCHUNK; ++c) M = fmaxf(M, p0[c * 66]);
  float L = 0.f, o = 0.f;
#pragma unroll 8
  for (int c = 0; c < NCHUNK; ++c) {
    const float mc = p0[c * 66];
    if (mc > -INFINITY) {
      const float w = __expf(mc - M);
      L += p0[c * 66 + 1] * w;
      o = fmaf(p0[c * 66 + 2 + d], w, o);
    }
  }
  attn[(size_t)b * DIM + h * HEAD_DIM + d] = o / L;
}

// ---------------- Kernel D: output projection ----------------
__global__ __launch_bounds__(256) void o_proj(
    const float* __restrict__ attn, const float* __restrict__ Wo,
    float* __restrict__ out) {
  __shared__ float tok[BATCH * DIM];
  for (int idx = threadIdx.x; idx < BATCH * DIM; idx += 256)
    tok[idx] = attn[idx];
  __syncthreads();

  const int wave = threadIdx.x >> 6;
  const int lane = threadIdx.x & 63;
  const int i0 = blockIdx.x * 16 + wave * 4;

  float acc[4][16];
#pragma unroll
  for (int ii = 0; ii < 4; ++ii)
#pragma unroll
    for (int b = 0; b < 16; ++b) acc[ii][b] = 0.f;

  for (int t = 0; t < 16; ++t) {
    const int j = t * 64 + lane;
    float tk[16];
#pragma unroll
    for (int b = 0; b < 16; ++b) tk[b] = tok[b * DIM + j];
#pragma unroll
    for (int ii = 0; ii < 4; ++ii) {
      const float w = Wo[(size_t)(i0 + ii) * DIM + j];
#pragma unroll
      for (int b = 0; b < 16; ++b) acc[ii][b] = fmaf(w, tk[b], acc[ii][b]);
    }
  }

#pragma unroll
  for (int ii = 0; ii < 4; ++ii)
#pragma unroll
    for (int b = 0; b < 16; ++b) {
      float v = acc[ii][b];
#pragma unroll
      for (int m = 32; m >= 1; m >>= 1) v += __shfl_xor(v, m);
      if (lane == 0) out[(size_t)b * DIM + i0 + ii] = v;
    }
}

extern "C" void kernel_launch(void* const* d_in, const int* in_sizes, int n_in,
                              void* d_out, int out_size, void* d_ws, size_t ws_size,
                              hipStream_t stream) {
  const float* token = (const float*)d_in[0];
  const float* kc = (const float*)d_in[1];
  const float* vc = (const float*)d_in[2];
  const float* Wq = (const float*)d_in[3];
  const float* Wk = (const float*)d_in[4];
  const float* Wv = (const float*)d_in[5];
  const float* Wo = (const float*)d_in[6];
  const int* pos = (const int*)d_in[7];
  float* out = (float*)d_out;
  float* ws = (float*)d_ws;

  // workspace layout (floats):
  //  [0, 49152)   : q,k,v projections (3 x 16 x 1024)
  //  then         : attention partials 16*16*NCHUNK*66
  //  then         : combined attention output 16 x 1024
  float* qkv = ws;
  float* part = ws + 3 * BATCH * DIM;
  float* attn = part + (size_t)BATCH * HEADS * NCHUNK * 66;

  hipLaunchKernelGGL(qkv_proj, dim3(64, 3), dim3(256), 0, stream,
                     token, Wq, Wk, Wv, qkv);
  hipLaunchKernelGGL(attn_partial, dim3(NCHUNK, BATCH), dim3(256), 0,
                     stream, kc, vc, qkv, pos, part);
  hipLaunchKernelGGL(attn_combine, dim3(BATCH * HEADS), dim3(64), 0, stream,
                     part, attn);
  hipLaunchKernelGGL(o_proj, dim3(64), dim3(256), 0, stream, attn, Wo, out);
  (void)in_sizes; (void)n_in; (void)out_size; (void)ws_size;
}